// Round 5
// baseline (284.277 us; speedup 1.0000x reference)
//
#include <hip/hip_runtime.h>
#include <hip/hip_bf16.h>
#include <math.h>

#define D    1024
#define C    16
#define N    256
#define TOK  8192   // B*S
#define DH   512    // D/2
#define RT_T 16     // route: tokens per block
#define WLMAX 1152  // worklist capacity (>= 130 groups * 8 stride)

using bf16x8 = __attribute__((ext_vector_type(8))) short;
using f32x4  = __attribute__((ext_vector_type(4))) float;

__device__ __forceinline__ float gelu_exact(float v) {
    return 0.5f * v * (1.0f + erff(v * 0.70710678118654752440f));
}
__device__ __forceinline__ float sigmoidf_(float z) {
    return 1.0f / (1.0f + expf(-z));
}
__device__ __forceinline__ short f2bf(float f) {          // RNE f32->bf16
    unsigned u = __float_as_uint(f);
    unsigned r = u + 0x7FFF + ((u >> 16) & 1);
    return (short)(r >> 16);
}
__device__ __forceinline__ float bf2f(short s) {
    return __uint_as_float(((unsigned)(unsigned short)s) << 16);
}

// ---------------------------------------------------------------------------
// prep: col_emb norms
// ---------------------------------------------------------------------------
__global__ void prep_kernel(const float* __restrict__ col_emb, float* __restrict__ cnorm) {
    const int tid = threadIdx.x;              // 256
    const int c = tid >> 4, l = tid & 15;
    float acc = 0.f;
    for (int j = 0; j < 64; ++j) {
        float v = col_emb[c * D + l + 16 * j];
        acc += v * v;
    }
    for (int off = 8; off; off >>= 1) acc += __shfl_xor(acc, off, 16);
    if (l == 0) cnorm[c] = fmaxf(sqrtf(acc), 1e-12f);
}

// ---------------------------------------------------------------------------
// straight f32 -> bf16 convert (x)
// ---------------------------------------------------------------------------
__global__ __launch_bounds__(256) void conv_kernel(const float* __restrict__ src,
                                                   short* __restrict__ dst, int n4) {
    int i = blockIdx.x * 256 + threadIdx.x;
    const int stride = gridDim.x * 256;
    for (; i < n4; i += stride) {
        const float4 v = ((const float4*)src)[i];
        short4 o;
        o.x = f2bf(v.x); o.y = f2bf(v.y); o.z = f2bf(v.z); o.w = f2bf(v.w);
        ((short4*)dst)[i] = o;
    }
}

// ---------------------------------------------------------------------------
// transpose + convert: src f32 [R][Cc] -> dst bf16 [Cc][R]  (batched over z)
// ---------------------------------------------------------------------------
__global__ __launch_bounds__(256) void tconv_kernel(const float* __restrict__ src0,
        short* __restrict__ dst0, int R, int Cc) {
    __shared__ float tile[64][65];
    const int tid = threadIdx.x;
    const size_t bofs = (size_t)blockIdx.z * R * Cc;
    const float* src = src0 + bofs;
    short* dst = dst0 + bofs;
    const int cBase = blockIdx.x * 64;
    const int rBase = blockIdx.y * 64;
    const int rr = tid >> 4;           // 0..15
    const int cq = (tid & 15) * 4;
    #pragma unroll
    for (int h = 0; h < 4; ++h) {
        const int r = h * 16 + rr;
        const float4 v = *(const float4*)&src[(size_t)(rBase + r) * Cc + cBase + cq];
        tile[r][cq + 0] = v.x; tile[r][cq + 1] = v.y;
        tile[r][cq + 2] = v.z; tile[r][cq + 3] = v.w;
    }
    __syncthreads();
    #pragma unroll
    for (int h = 0; h < 4; ++h) {
        const int cc = h * 16 + rr;    // output row (= src col)
        short4 o;
        o.x = f2bf(tile[cq + 0][cc]);
        o.y = f2bf(tile[cq + 1][cc]);
        o.z = f2bf(tile[cq + 2][cc]);
        o.w = f2bf(tile[cq + 3][cc]);
        *(short4*)&dst[(size_t)(cBase + cc) * R + rBase + cq] = o;
    }
}

// ---------------------------------------------------------------------------
// gate GEMM: H = gelu(xb @ w1T^T + b1), 64x64 tile, BK=64, 2x2 waves
// ---------------------------------------------------------------------------
__global__ __launch_bounds__(256) void gate_mfma_kernel(
        const short* __restrict__ Ag, const short* __restrict__ BTg,
        const float* __restrict__ bias, short* __restrict__ outb) {
    __shared__ short As[64 * 64];
    __shared__ short Bs[64 * 64];
    const int tid = threadIdx.x;
    const int lane = tid & 63;
    const int wave = tid >> 6;
    const int wr = wave >> 1, wc = wave & 1;

    const int rA0 = tid >> 3;                // 0..31
    const int rA1 = rA0 + 32;                // 32..63
    const int bo  = (tid & 7) * 16;          // byte offset in 128B chunk
    const size_t m0 = (size_t)blockIdx.x * 64;
    const char* gA0 = (const char*)Ag + (m0 + rA0) * (D * 2) + bo;
    const char* gA1 = (const char*)Ag + (m0 + rA1) * (D * 2) + bo;
    const size_t bbase = (size_t)blockIdx.y * 64 * (D * 2);
    const char* gB0 = (const char*)BTg + bbase + (size_t)rA0 * (D * 2) + bo;
    const char* gB1 = (const char*)BTg + bbase + (size_t)rA1 * (D * 2) + bo;
    char* const wA0 = (char*)As + rA0 * 128 + (bo ^ ((rA0 & 7) << 4));
    char* const wA1 = (char*)As + rA1 * 128 + (bo ^ ((rA1 & 7) << 4));
    char* const wB0 = (char*)Bs + rA0 * 128 + (bo ^ ((rA0 & 7) << 4));
    char* const wB1 = (char*)Bs + rA1 * 128 + (bo ^ ((rA1 & 7) << 4));

    const int mrow = wr * 32 + (lane & 15);
    const int nrow = wc * 32 + (lane & 15);
    const int kbB  = (lane >> 4) * 16;
    const int swm  = (mrow & 7) << 4;
    const int swn  = (nrow & 7) << 4;

    f32x4 acc[2][2] = {};
    for (int kk = 0; kk < D / 64; ++kk) {
        *(bf16x8*)wA0 = *(const bf16x8*)gA0;
        *(bf16x8*)wA1 = *(const bf16x8*)gA1;
        *(bf16x8*)wB0 = *(const bf16x8*)gB0;
        *(bf16x8*)wB1 = *(const bf16x8*)gB1;
        gA0 += 128; gA1 += 128; gB0 += 128; gB1 += 128;
        __syncthreads();
        #pragma unroll
        for (int ks = 0; ks < 2; ++ks) {
            bf16x8 aF[2], bF[2];
            #pragma unroll
            for (int i = 0; i < 2; ++i)
                aF[i] = *(const bf16x8*)((const char*)As + (mrow + i * 16) * 128
                                         + ((kbB + ks * 64) ^ swm));
            #pragma unroll
            for (int j = 0; j < 2; ++j)
                bF[j] = *(const bf16x8*)((const char*)Bs + (nrow + j * 16) * 128
                                         + ((kbB + ks * 64) ^ swn));
            #pragma unroll
            for (int i = 0; i < 2; ++i)
                #pragma unroll
                for (int j = 0; j < 2; ++j)
                    acc[i][j] = __builtin_amdgcn_mfma_f32_16x16x32_bf16(
                                    aF[i], bF[j], acc[i][j], 0, 0, 0);
        }
        __syncthreads();
    }
    const int crow = (lane >> 4) * 4;
    const int ccol = lane & 15;
    const int n0 = blockIdx.y * 64;
    #pragma unroll
    for (int i = 0; i < 2; ++i)
        #pragma unroll
        for (int j = 0; j < 2; ++j) {
            const int n = n0 + wc * 32 + j * 16 + ccol;
            const float bb = bias[n];
            #pragma unroll
            for (int r = 0; r < 4; ++r) {
                const int m = (int)m0 + wr * 32 + i * 16 + crow + r;
                outb[(size_t)m * DH + n] = f2bf(gelu_exact(acc[i][j][r] + bb));
            }
        }
}

// ---------------------------------------------------------------------------
// fused column kernel: per 64-token group of one column
//   act = gelu(xb[tok] @ WcT[col]^T + bc) * wgt   (K=1024, out 64x256 -> LDS)
//   y   = act @ pwT[col]^T + pb + x               (K=256,  out 64x1024 -> out)
// worklist entry: (col<<20)|start, stride-8 layout for XCD L2 affinity
// ---------------------------------------------------------------------------
__global__ __launch_bounds__(256) void col_fused_kernel(
        const short* __restrict__ xb, const short* __restrict__ WcT,
        const short* __restrict__ pwT, const float* __restrict__ bc,
        const float* __restrict__ pb, const float* __restrict__ x,
        const int* __restrict__ counts, const int* __restrict__ offs,
        const int* __restrict__ order, const float* __restrict__ wgt,
        const int* __restrict__ wl, float* __restrict__ outf) {
    __shared__ char smem[73728];          // 72 KB
    __shared__ int tokl[64];
    __shared__ float wgl[64];
    char* const As   = smem;              //  8 KB  (G1 A tile)
    char* const B1s  = smem + 8192;       // 32 KB  (G1 B tile)
    char* const B2s  = smem;              // 32 KB  (G2 B tile, aliases As+B1s)
    char* const actS = smem + 40960;      // 32 KB  act[64][256] bf16

    const int e = wl[blockIdx.x];
    if (e < 0) return;
    const int col = e >> 20;
    const int start = e & 0xFFFFF;
    const int cnt = counts[col];
    const int nt = min(64, cnt - start);
    const int base = offs[col] + start;
    const int tid = threadIdx.x;
    const int lane = tid & 63;
    const int wv = tid >> 6;

    if (tid < 64) {
        const int i = tid < nt ? tid : nt - 1;
        const int t = order[base + i];
        tokl[tid] = t;
        wgl[tid] = wgt[t];
    }
    __syncthreads();

    const int mrow = lane & 15;
    const int kb0 = (lane >> 4) * 16;

    // ---------------- GEMM1 ----------------
    const int rA = tid >> 2;              // 0..63
    const int qA = (tid & 3) * 32;        // 0/32/64/96
    const int swA = (rA & 7) << 4;
    const char* gA = (const char*)xb + (size_t)tokl[rA] * (D * 2) + qA;
    const char* gB = (const char*)WcT + ((size_t)col * N + tid) * (D * 2);
    const int swB = (tid & 7) << 4;

    f32x4 acc1[4][4] = {};
    for (int kk = 0; kk < 16; ++kk) {
        *(bf16x8*)(As + rA * 128 + (qA ^ swA)) = *(const bf16x8*)(gA);
        *(bf16x8*)(As + rA * 128 + ((qA + 16) ^ swA)) = *(const bf16x8*)(gA + 16);
        gA += 128;
        {
            const char* s = gB + kk * 128;
            char* dbase = B1s + tid * 128;
            #pragma unroll
            for (int h = 0; h < 8; ++h)
                *(bf16x8*)(dbase + ((h * 16) ^ swB)) = *(const bf16x8*)(s + h * 16);
        }
        __syncthreads();
        #pragma unroll
        for (int ks = 0; ks < 2; ++ks) {
            const int kb = kb0 + ks * 64;
            bf16x8 aF[4], bF[4];
            #pragma unroll
            for (int i = 0; i < 4; ++i) {
                const int m = i * 16 + mrow;
                aF[i] = *(const bf16x8*)(As + m * 128 + (kb ^ ((m & 7) << 4)));
            }
            #pragma unroll
            for (int j = 0; j < 4; ++j) {
                const int n = wv * 64 + j * 16 + mrow;
                bF[j] = *(const bf16x8*)(B1s + n * 128 + (kb ^ ((n & 7) << 4)));
            }
            #pragma unroll
            for (int i = 0; i < 4; ++i)
                #pragma unroll
                for (int j = 0; j < 4; ++j)
                    acc1[i][j] = __builtin_amdgcn_mfma_f32_16x16x32_bf16(
                                     aF[i], bF[j], acc1[i][j], 0, 0, 0);
        }
        __syncthreads();
    }

    // act -> LDS (bf16, swizzled rows of 512B)
    #pragma unroll
    for (int i = 0; i < 4; ++i)
        #pragma unroll
        for (int j = 0; j < 4; ++j) {
            const int n = wv * 64 + j * 16 + (lane & 15);
            const float bb = bc[col * N + n];
            #pragma unroll
            for (int r = 0; r < 4; ++r) {
                const int m = i * 16 + (lane >> 4) * 4 + r;
                const float v = gelu_exact(acc1[i][j][r] + bb) * wgl[m];
                *(short*)(actS + m * 512 + ((n * 2) ^ ((m & 7) << 4))) = f2bf(v);
            }
        }
    __syncthreads();

    // ---------------- GEMM2 (16 d-tiles of 64) ----------------
    const int r2 = tid >> 2;              // 0..63
    const int q2 = (tid & 3) * 128;
    const int sw2 = (r2 & 7) << 4;
    for (int yd = 0; yd < 16; ++yd) {
        {
            const char* s = (const char*)pwT + ((size_t)col * D + yd * 64 + r2) * 512 + q2;
            char* dbase = B2s + r2 * 512;
            #pragma unroll
            for (int h = 0; h < 8; ++h)
                *(bf16x8*)(dbase + ((q2 + h * 16) ^ sw2)) = *(const bf16x8*)(s + h * 16);
        }
        __syncthreads();
        f32x4 acc2[4] = {};
        const int m = wv * 16 + mrow;
        const int swm2 = (m & 7) << 4;
        #pragma unroll
        for (int km = 0; km < 8; ++km) {
            const int kb = km * 64 + kb0;
            const bf16x8 aF = *(const bf16x8*)(actS + m * 512 + (kb ^ swm2));
            #pragma unroll
            for (int j = 0; j < 4; ++j) {
                const int dr = j * 16 + mrow;
                const bf16x8 bF = *(const bf16x8*)(B2s + dr * 512 + (kb ^ ((dr & 7) << 4)));
                acc2[j] = __builtin_amdgcn_mfma_f32_16x16x32_bf16(aF, bF, acc2[j], 0, 0, 0);
            }
        }
        #pragma unroll
        for (int j = 0; j < 4; ++j) {
            const int d = yd * 64 + j * 16 + (lane & 15);
            const float pbv = pb[d];
            #pragma unroll
            for (int r = 0; r < 4; ++r) {
                const int mo = wv * 16 + (lane >> 4) * 4 + r;
                if (mo < nt) {
                    const size_t ofs = (size_t)tokl[mo] * D + d;
                    outf[ofs] = acc2[j][r] + pbv + x[ofs];
                }
            }
        }
        __syncthreads();
    }
}

// ---------------------------------------------------------------------------
// route: weights-in-registers, activations streamed coalesced (round-4 winner)
// ---------------------------------------------------------------------------
__global__ __launch_bounds__(256) void route_kernel(
        const float* __restrict__ x, const short* __restrict__ Hb,
        const float* __restrict__ col_emb, const float* __restrict__ cnorm,
        const float* __restrict__ w2, const float* __restrict__ b2,
        int* __restrict__ idx, float* __restrict__ wgt) {
    __shared__ float P[256][33];
    __shared__ float Q[8][33];
    __shared__ float SSW[4];
    __shared__ float FL[RT_T][34];
    const int tid = threadIdx.x;
    const int lane = tid & 63;
    const int t0 = blockIdx.x * RT_T;
    const int swz = (tid & 7) << 2;

    float4 ce[C];
    #pragma unroll
    for (int c = 0; c < C; ++c)
        ce[c] = *(const float4*)&col_emb[c * D + tid * 4];
    float w2r[2][C];
    #pragma unroll
    for (int r2 = 0; r2 < 2; ++r2)
        #pragma unroll
        for (int cq = 0; cq < 4; ++cq) {
            const float4 v = *(const float4*)&w2[(tid * 2 + r2) * C + cq * 4];
            w2r[r2][cq * 4 + 0] = v.x; w2r[r2][cq * 4 + 1] = v.y;
            w2r[r2][cq * 4 + 2] = v.z; w2r[r2][cq * 4 + 3] = v.w;
        }

    for (int ti = 0; ti < RT_T; ++ti) {
        const int t = t0 + ti;
        const float4 xv = *(const float4*)&x[(size_t)t * D + tid * 4];
        const unsigned hu = *(const unsigned*)&Hb[(size_t)t * DH + tid * 2];
        const float h0 = bf2f((short)(hu & 0xffff));
        const float h1 = bf2f((short)(hu >> 16));
        float pv[32];
        #pragma unroll
        for (int c = 0; c < C; ++c)
            pv[c] = xv.x * ce[c].x + xv.y * ce[c].y + xv.z * ce[c].z + xv.w * ce[c].w;
        #pragma unroll
        for (int c = 0; c < C; ++c)
            pv[C + c] = h0 * w2r[0][c] + h1 * w2r[1][c];
        float ssp = xv.x * xv.x + xv.y * xv.y + xv.z * xv.z + xv.w * xv.w;
        #pragma unroll
        for (int off = 32; off; off >>= 1) ssp += __shfl_xor(ssp, off);
        if (lane == 0) SSW[tid >> 6] = ssp;
        #pragma unroll
        for (int c = 0; c < 32; ++c)
            P[tid][c ^ swz] = pv[c];
        __syncthreads();
        {
            const int v = tid & 31, jj = tid >> 5;
            float s = 0.f;
            #pragma unroll
            for (int k = 0; k < 32; ++k) {
                const int row = jj * 32 + k;
                s += P[row][v ^ ((row & 7) << 2)];
            }
            Q[jj][v] = s;
        }
        __syncthreads();
        if (tid < 32) {
            float f = 0.f;
            #pragma unroll
            for (int j2 = 0; j2 < 8; ++j2) f += Q[j2][tid];
            FL[ti][tid] = f;
        } else if (tid == 32) {
            FL[ti][32] = SSW[0] + SSW[1] + SSW[2] + SSW[3];
        }
        __syncthreads();
    }

    if (tid < RT_T) {
        const int t = t0 + tid;
        const float xn = fmaxf(sqrtf(FL[tid][32]), 1e-12f);
        float logit[C];
        #pragma unroll
        for (int c = 0; c < C; ++c)
            logit[c] = FL[tid][c] / (xn * cnorm[c])
                     + sigmoidf_(FL[tid][C + c] + b2[c]);
        float mx = logit[0]; int am = 0;
        #pragma unroll
        for (int c = 1; c < C; ++c)
            if (logit[c] > mx) { mx = logit[c]; am = c; }
        float se = 0.f;
        #pragma unroll
        for (int c = 0; c < C; ++c) se += expf(logit[c] - mx);
        idx[t] = am;
        wgt[t] = 1.f / se;
    }
}

// ---------------------------------------------------------------------------
// histogram + prefix + worklist (single block)
// ---------------------------------------------------------------------------
__global__ __launch_bounds__(256) void hist_kernel(const int* __restrict__ idx,
        int* __restrict__ counts, int* __restrict__ offs, int* __restrict__ cursor,
        int* __restrict__ wl) {
    __shared__ int h[C];
    const int tid = threadIdx.x;
    if (tid < C) h[tid] = 0;
    for (int i = tid; i < WLMAX; i += 256) wl[i] = -1;
    __syncthreads();
    for (int t = tid; t < TOK; t += 256) atomicAdd(&h[idx[t]], 1);
    __syncthreads();
    if (tid == 0) {
        int s = 0;
        int slots[8] = {0, 0, 0, 0, 0, 0, 0, 0};
        for (int c = 0; c < C; ++c) {
            counts[c] = h[c]; offs[c] = s; cursor[c] = s; s += h[c];
            const int b = c & 7;
            for (int st = 0; st < h[c]; st += 64) {
                wl[slots[b] * 8 + b] = (c << 20) | st;
                slots[b]++;
            }
        }
    }
}

// ---------------------------------------------------------------------------
// scatter: block-local ranges -> 16 global atomics per block
// ---------------------------------------------------------------------------
__global__ __launch_bounds__(256) void scatter_kernel(const int* __restrict__ idx,
        int* __restrict__ cursor, int* __restrict__ order) {
    __shared__ int lh[C];
    __shared__ int lbase[C];
    const int tid = threadIdx.x;
    const int t = blockIdx.x * 256 + tid;
    if (tid < C) lh[tid] = 0;
    __syncthreads();
    const int c = idx[t];
    const int p = atomicAdd(&lh[c], 1);
    __syncthreads();
    if (tid < C) lbase[tid] = atomicAdd(&cursor[tid], lh[tid]);
    __syncthreads();
    order[lbase[c] + p] = t;
}

// ---------------------------------------------------------------------------
// layernorm, in-place on out
// ---------------------------------------------------------------------------
__global__ __launch_bounds__(256) void ln_kernel(float* __restrict__ out,
        const float* __restrict__ g, const float* __restrict__ b) {
    __shared__ float wr_[4], wr2[4];
    const int t = blockIdx.x, tid = threadIdx.x;
    const float4 v = *(const float4*)&out[(size_t)t * D + tid * 4];
    float s = v.x + v.y + v.z + v.w;
    float s2 = v.x * v.x + v.y * v.y + v.z * v.z + v.w * v.w;
    for (int off = 32; off; off >>= 1) { s += __shfl_xor(s, off); s2 += __shfl_xor(s2, off); }
    if ((tid & 63) == 0) { wr_[tid >> 6] = s; wr2[tid >> 6] = s2; }
    __syncthreads();
    const float sum = wr_[0] + wr_[1] + wr_[2] + wr_[3];
    const float sum2 = wr2[0] + wr2[1] + wr2[2] + wr2[3];
    const float mu = sum * (1.f / D);
    const float var = sum2 * (1.f / D) - mu * mu;
    const float inv = rsqrtf(var + 1e-5f);
    const float4 g4 = *(const float4*)&g[tid * 4];
    const float4 b4 = *(const float4*)&b[tid * 4];
    float4 o;
    o.x = (v.x - mu) * inv * g4.x + b4.x;
    o.y = (v.y - mu) * inv * g4.y + b4.y;
    o.z = (v.z - mu) * inv * g4.z + b4.z;
    o.w = (v.w - mu) * inv * g4.w + b4.w;
    *(float4*)&out[(size_t)t * D + tid * 4] = o;
}

// ---------------------------------------------------------------------------
extern "C" void kernel_launch(void* const* d_in, const int* in_sizes, int n_in,
                              void* d_out, int out_size, void* d_ws, size_t ws_size,
                              hipStream_t stream) {
    const float* x       = (const float*)d_in[0];
    const float* col_emb = (const float*)d_in[1];
    const float* gate_w1 = (const float*)d_in[2];
    const float* gate_b1 = (const float*)d_in[3];
    const float* gate_w2 = (const float*)d_in[4];
    const float* gate_b2 = (const float*)d_in[5];
    const float* W_cols  = (const float*)d_in[6];
    const float* b_cols  = (const float*)d_in[7];
    const float* proj_w  = (const float*)d_in[8];
    const float* proj_b  = (const float*)d_in[9];
    const float* ln_g    = (const float*)d_in[10];
    const float* ln_b    = (const float*)d_in[11];
    float* out = (float*)d_out;

    char* w = (char*)d_ws;
    short* xb    = (short*)w;  w += (size_t)TOK * D * 2;           // 16 MB
    short* Hb    = (short*)w;  w += (size_t)TOK * DH * 2;          //  8 MB
    short* w1T   = (short*)w;  w += (size_t)DH * D * 2;            //  1 MB
    short* WcT   = (short*)w;  w += (size_t)C * N * D * 2;         //  8 MB
    short* pwT   = (short*)w;  w += (size_t)C * D * N * 2;         //  8 MB
    float* wgt   = (float*)w;  w += TOK * 4;
    float* cnorm = (float*)w;  w += 64;
    int*   idx   = (int*)w;    w += TOK * 4;
    int*   order = (int*)w;    w += TOK * 4;
    int*   counts= (int*)w;    w += 64;
    int*   offs  = (int*)w;    w += 64;
    int*   cursor= (int*)w;    w += 64;
    int*   wl    = (int*)w;    w += WLMAX * 4;

    hipLaunchKernelGGL(prep_kernel, dim3(1), dim3(256), 0, stream, col_emb, cnorm);
    hipLaunchKernelGGL(conv_kernel, dim3(2048), dim3(256), 0, stream,
                       x, xb, TOK * D / 4);
    hipLaunchKernelGGL(tconv_kernel, dim3(DH / 64, D / 64, 1), dim3(256), 0, stream,
                       gate_w1, w1T, D, DH);
    hipLaunchKernelGGL(tconv_kernel, dim3(N / 64, D / 64, C), dim3(256), 0, stream,
                       W_cols, WcT, D, N);
    hipLaunchKernelGGL(tconv_kernel, dim3(D / 64, N / 64, C), dim3(256), 0, stream,
                       proj_w, pwT, N, D);
    hipLaunchKernelGGL(gate_mfma_kernel, dim3(TOK / 64, DH / 64), dim3(256), 0, stream,
                       xb, w1T, gate_b1, Hb);
    hipLaunchKernelGGL(route_kernel, dim3(TOK / RT_T), dim3(256), 0, stream,
                       x, Hb, col_emb, cnorm, gate_w2, gate_b2, idx, wgt);
    hipLaunchKernelGGL(hist_kernel, dim3(1), dim3(256), 0, stream,
                       idx, counts, offs, cursor, wl);
    hipLaunchKernelGGL(scatter_kernel, dim3(TOK / 256), dim3(256), 0, stream,
                       idx, cursor, order);
    hipLaunchKernelGGL(col_fused_kernel, dim3(WLMAX), dim3(256), 0, stream,
                       xb, WcT, pwT, b_cols, proj_b, x,
                       counts, offs, order, wgt, wl, out);
    hipLaunchKernelGGL(ln_kernel, dim3(TOK), dim3(256), 0, stream, out, ln_g, ln_b);
}

// Round 6
// 167.536 us; speedup vs baseline: 1.6968x; 1.6968x over previous
//
#include <hip/hip_runtime.h>
#include <hip/hip_bf16.h>
#include <math.h>

#define D    1024
#define C    16
#define N    256
#define TOK  8192   // B*S
#define DH   512    // D/2
#define RT_T 16     // route: tokens per block
#define WLG  160    // worklist slots (>=144 worst-case groups), stride-8 buckets
#define BCAP 20     // per-bucket capacity (8*20 = 160)

using bf16x8 = __attribute__((ext_vector_type(8))) short;
using f32x4  = __attribute__((ext_vector_type(4))) float;

__device__ __forceinline__ float gelu_exact(float v) {
    return 0.5f * v * (1.0f + erff(v * 0.70710678118654752440f));
}
__device__ __forceinline__ float sigmoidf_(float z) {
    return 1.0f / (1.0f + expf(-z));
}
__device__ __forceinline__ short f2bf(float f) {          // RNE f32->bf16
    unsigned u = __float_as_uint(f);
    unsigned r = u + 0x7FFF + ((u >> 16) & 1);
    return (short)(r >> 16);
}
__device__ __forceinline__ float bf2f(short s) {
    return __uint_as_float(((unsigned)(unsigned short)s) << 16);
}

// ---------------------------------------------------------------------------
// prep: col_emb norms
// ---------------------------------------------------------------------------
__global__ void prep_kernel(const float* __restrict__ col_emb, float* __restrict__ cnorm) {
    const int tid = threadIdx.x;              // 256
    const int c = tid >> 4, l = tid & 15;
    float acc = 0.f;
    for (int j = 0; j < 64; ++j) {
        float v = col_emb[c * D + l + 16 * j];
        acc += v * v;
    }
    for (int off = 8; off; off >>= 1) acc += __shfl_xor(acc, off, 16);
    if (l == 0) cnorm[c] = fmaxf(sqrtf(acc), 1e-12f);
}

// ---------------------------------------------------------------------------
// straight f32 -> bf16 convert (x)
// ---------------------------------------------------------------------------
__global__ __launch_bounds__(256) void conv_kernel(const float* __restrict__ src,
                                                   short* __restrict__ dst, int n4) {
    int i = blockIdx.x * 256 + threadIdx.x;
    const int stride = gridDim.x * 256;
    for (; i < n4; i += stride) {
        const float4 v = ((const float4*)src)[i];
        short4 o;
        o.x = f2bf(v.x); o.y = f2bf(v.y); o.z = f2bf(v.z); o.w = f2bf(v.w);
        ((short4*)dst)[i] = o;
    }
}

// ---------------------------------------------------------------------------
// transpose + convert: src f32 [R][Cc] -> dst bf16 [Cc][R]  (batched over z)
// ---------------------------------------------------------------------------
__global__ __launch_bounds__(256) void tconv_kernel(const float* __restrict__ src0,
        short* __restrict__ dst0, int R, int Cc) {
    __shared__ float tile[64][65];
    const int tid = threadIdx.x;
    const size_t bofs = (size_t)blockIdx.z * R * Cc;
    const float* src = src0 + bofs;
    short* dst = dst0 + bofs;
    const int cBase = blockIdx.x * 64;
    const int rBase = blockIdx.y * 64;
    const int rr = tid >> 4;           // 0..15
    const int cq = (tid & 15) * 4;
    #pragma unroll
    for (int h = 0; h < 4; ++h) {
        const int r = h * 16 + rr;
        const float4 v = *(const float4*)&src[(size_t)(rBase + r) * Cc + cBase + cq];
        tile[r][cq + 0] = v.x; tile[r][cq + 1] = v.y;
        tile[r][cq + 2] = v.z; tile[r][cq + 3] = v.w;
    }
    __syncthreads();
    #pragma unroll
    for (int h = 0; h < 4; ++h) {
        const int cc = h * 16 + rr;    // output row (= src col)
        short4 o;
        o.x = f2bf(tile[cq + 0][cc]);
        o.y = f2bf(tile[cq + 1][cc]);
        o.z = f2bf(tile[cq + 2][cc]);
        o.w = f2bf(tile[cq + 3][cc]);
        *(short4*)&dst[(size_t)(cBase + cc) * R + rBase + cq] = o;
    }
}

// ---------------------------------------------------------------------------
// gate GEMM: H = gelu(xb @ w1T^T + b1), 64x64 tile, BK=64, 2x2 waves
// ---------------------------------------------------------------------------
__global__ __launch_bounds__(256) void gate_mfma_kernel(
        const short* __restrict__ Ag, const short* __restrict__ BTg,
        const float* __restrict__ bias, short* __restrict__ outb) {
    __shared__ short As[64 * 64];
    __shared__ short Bs[64 * 64];
    const int tid = threadIdx.x;
    const int lane = tid & 63;
    const int wave = tid >> 6;
    const int wr = wave >> 1, wc = wave & 1;

    const int rA0 = tid >> 3;                // 0..31
    const int rA1 = rA0 + 32;                // 32..63
    const int bo  = (tid & 7) * 16;          // byte offset in 128B chunk
    const size_t m0 = (size_t)blockIdx.x * 64;
    const char* gA0 = (const char*)Ag + (m0 + rA0) * (D * 2) + bo;
    const char* gA1 = (const char*)Ag + (m0 + rA1) * (D * 2) + bo;
    const size_t bbase = (size_t)blockIdx.y * 64 * (D * 2);
    const char* gB0 = (const char*)BTg + bbase + (size_t)rA0 * (D * 2) + bo;
    const char* gB1 = (const char*)BTg + bbase + (size_t)rA1 * (D * 2) + bo;
    char* const wA0 = (char*)As + rA0 * 128 + (bo ^ ((rA0 & 7) << 4));
    char* const wA1 = (char*)As + rA1 * 128 + (bo ^ ((rA1 & 7) << 4));
    char* const wB0 = (char*)Bs + rA0 * 128 + (bo ^ ((rA0 & 7) << 4));
    char* const wB1 = (char*)Bs + rA1 * 128 + (bo ^ ((rA1 & 7) << 4));

    const int mrow = wr * 32 + (lane & 15);
    const int nrow = wc * 32 + (lane & 15);
    const int kbB  = (lane >> 4) * 16;
    const int swm  = (mrow & 7) << 4;
    const int swn  = (nrow & 7) << 4;

    f32x4 acc[2][2] = {};
    for (int kk = 0; kk < D / 64; ++kk) {
        *(bf16x8*)wA0 = *(const bf16x8*)gA0;
        *(bf16x8*)wA1 = *(const bf16x8*)gA1;
        *(bf16x8*)wB0 = *(const bf16x8*)gB0;
        *(bf16x8*)wB1 = *(const bf16x8*)gB1;
        gA0 += 128; gA1 += 128; gB0 += 128; gB1 += 128;
        __syncthreads();
        #pragma unroll
        for (int ks = 0; ks < 2; ++ks) {
            bf16x8 aF[2], bF[2];
            #pragma unroll
            for (int i = 0; i < 2; ++i)
                aF[i] = *(const bf16x8*)((const char*)As + (mrow + i * 16) * 128
                                         + ((kbB + ks * 64) ^ swm));
            #pragma unroll
            for (int j = 0; j < 2; ++j)
                bF[j] = *(const bf16x8*)((const char*)Bs + (nrow + j * 16) * 128
                                         + ((kbB + ks * 64) ^ swn));
            #pragma unroll
            for (int i = 0; i < 2; ++i)
                #pragma unroll
                for (int j = 0; j < 2; ++j)
                    acc[i][j] = __builtin_amdgcn_mfma_f32_16x16x32_bf16(
                                    aF[i], bF[j], acc[i][j], 0, 0, 0);
        }
        __syncthreads();
    }
    const int crow = (lane >> 4) * 4;
    const int ccol = lane & 15;
    const int n0 = blockIdx.y * 64;
    #pragma unroll
    for (int i = 0; i < 2; ++i)
        #pragma unroll
        for (int j = 0; j < 2; ++j) {
            const int n = n0 + wc * 32 + j * 16 + ccol;
            const float bb = bias[n];
            #pragma unroll
            for (int r = 0; r < 4; ++r) {
                const int m = (int)m0 + wr * 32 + i * 16 + crow + r;
                outb[(size_t)m * DH + n] = f2bf(gelu_exact(acc[i][j][r] + bb));
            }
        }
}

// ---------------------------------------------------------------------------
// grouped column GEMMs, worklist-driven. 64x64 tile, BK=64, 2x2 waves.
// wl entry: (col<<24)|(nt<<16)|baseSlot, -1 = empty slot.
// MODE 1: act = gelu(xb[tok] @ WcT[col]^T + bc)*wgt -> actb[slot]
// MODE 2: y   = actb[slot] @ pwT[col]^T + pb + x    -> out rows (scatter)
// ---------------------------------------------------------------------------
template<int MODE>
__global__ __launch_bounds__(256) void mfma_tile(
        const short* __restrict__ Ag, const short* __restrict__ BTg,
        const float* __restrict__ bias, const float* __restrict__ x,
        const int* __restrict__ order, const float* __restrict__ wgt,
        const int* __restrict__ wl,
        short* __restrict__ outb, float* __restrict__ outf) {
    constexpr int KDIM = (MODE == 2) ? N : D;
    constexpr int KSTEPS = KDIM / 64;
    __shared__ short As[64 * 64];
    __shared__ short Bs[64 * 64];
    __shared__ int   tokl[64];
    __shared__ float wgl[64];

    const int e = wl[blockIdx.x];
    if (e < 0) return;
    const int col  = e >> 24;
    const int nt   = (e >> 16) & 0xFF;
    const int base = e & 0xFFFF;

    const int tid = threadIdx.x;
    const int lane = tid & 63;
    const int wave = tid >> 6;
    const int wr = wave >> 1, wc = wave & 1;

    if (tid < 64) {
        const int i = tid < nt ? tid : nt - 1;
        const int t = order[base + i];
        tokl[tid] = t;
        if (MODE == 1) wgl[tid] = wgt[t];
    }
    __syncthreads();

    const int rA0 = tid >> 3;                // 0..31
    const int rA1 = rA0 + 32;                // 32..63
    const int bo  = (tid & 7) * 16;          // byte offset in 128B chunk
    const char* gA0; const char* gA1;
    if (MODE == 1) {
        gA0 = (const char*)Ag + (size_t)tokl[rA0] * (D * 2) + bo;
        gA1 = (const char*)Ag + (size_t)tokl[rA1] * (D * 2) + bo;
    } else {
        const int s0 = base + min(rA0, nt - 1);
        const int s1 = base + min(rA1, nt - 1);
        gA0 = (const char*)Ag + (size_t)s0 * (N * 2) + bo;
        gA1 = (const char*)Ag + (size_t)s1 * (N * 2) + bo;
    }
    const size_t bRowB = KDIM * 2;
    size_t bbase;
    if (MODE == 1) bbase = ((size_t)col * N + blockIdx.y * 64) * bRowB;
    else           bbase = ((size_t)col * D + blockIdx.y * 64) * bRowB;
    const char* gB0 = (const char*)BTg + bbase + (size_t)rA0 * bRowB + bo;
    const char* gB1 = (const char*)BTg + bbase + (size_t)rA1 * bRowB + bo;

    char* const wA0 = (char*)As + rA0 * 128 + (bo ^ ((rA0 & 7) << 4));
    char* const wA1 = (char*)As + rA1 * 128 + (bo ^ ((rA1 & 7) << 4));
    char* const wB0 = (char*)Bs + rA0 * 128 + (bo ^ ((rA0 & 7) << 4));
    char* const wB1 = (char*)Bs + rA1 * 128 + (bo ^ ((rA1 & 7) << 4));

    const int mrow = wr * 32 + (lane & 15);
    const int nrow = wc * 32 + (lane & 15);
    const int kbB  = (lane >> 4) * 16;
    const int swm  = (mrow & 7) << 4;
    const int swn  = (nrow & 7) << 4;

    f32x4 acc[2][2] = {};
    for (int kk = 0; kk < KSTEPS; ++kk) {
        *(bf16x8*)wA0 = *(const bf16x8*)gA0;
        *(bf16x8*)wA1 = *(const bf16x8*)gA1;
        *(bf16x8*)wB0 = *(const bf16x8*)gB0;
        *(bf16x8*)wB1 = *(const bf16x8*)gB1;
        gA0 += 128; gA1 += 128; gB0 += 128; gB1 += 128;
        __syncthreads();
        #pragma unroll
        for (int ks = 0; ks < 2; ++ks) {
            bf16x8 aF[2], bF[2];
            #pragma unroll
            for (int i = 0; i < 2; ++i)
                aF[i] = *(const bf16x8*)((const char*)As + (mrow + i * 16) * 128
                                         + ((kbB + ks * 64) ^ swm));
            #pragma unroll
            for (int j = 0; j < 2; ++j)
                bF[j] = *(const bf16x8*)((const char*)Bs + (nrow + j * 16) * 128
                                         + ((kbB + ks * 64) ^ swn));
            #pragma unroll
            for (int i = 0; i < 2; ++i)
                #pragma unroll
                for (int j = 0; j < 2; ++j)
                    acc[i][j] = __builtin_amdgcn_mfma_f32_16x16x32_bf16(
                                    aF[i], bF[j], acc[i][j], 0, 0, 0);
        }
        __syncthreads();
    }

    const int crow = (lane >> 4) * 4;
    const int ccol = lane & 15;
    if (MODE == 1) {
        const int n0 = blockIdx.y * 64;
        #pragma unroll
        for (int i = 0; i < 2; ++i)
            #pragma unroll
            for (int j = 0; j < 2; ++j) {
                const int n = n0 + wc * 32 + j * 16 + ccol;
                const float bb = bias[col * N + n];
                #pragma unroll
                for (int r = 0; r < 4; ++r) {
                    const int il = wr * 32 + i * 16 + crow + r;
                    if (il < nt) {
                        const float v = gelu_exact(acc[i][j][r] + bb) * wgl[il];
                        outb[(size_t)(base + il) * N + n] = f2bf(v);
                    }
                }
            }
    } else {
        const int n0 = blockIdx.y * 64;
        #pragma unroll
        for (int i = 0; i < 2; ++i)
            #pragma unroll
            for (int j = 0; j < 2; ++j) {
                const int dcol = n0 + wc * 32 + j * 16 + ccol;
                const float bb = bias[dcol];
                #pragma unroll
                for (int r = 0; r < 4; ++r) {
                    const int il = wr * 32 + i * 16 + crow + r;
                    if (il < nt) {
                        const size_t ofs = (size_t)tokl[il] * D + dcol;
                        outf[ofs] = acc[i][j][r] + bb + x[ofs];
                    }
                }
            }
    }
}

// ---------------------------------------------------------------------------
// route: weights-in-registers, activations streamed coalesced (round-4 winner)
// ---------------------------------------------------------------------------
__global__ __launch_bounds__(256) void route_kernel(
        const float* __restrict__ x, const short* __restrict__ Hb,
        const float* __restrict__ col_emb, const float* __restrict__ cnorm,
        const float* __restrict__ w2, const float* __restrict__ b2,
        int* __restrict__ idx, float* __restrict__ wgt) {
    __shared__ float P[256][33];
    __shared__ float Q[8][33];
    __shared__ float SSW[4];
    __shared__ float FL[RT_T][34];
    const int tid = threadIdx.x;
    const int lane = tid & 63;
    const int t0 = blockIdx.x * RT_T;
    const int swz = (tid & 7) << 2;

    float4 ce[C];
    #pragma unroll
    for (int c = 0; c < C; ++c)
        ce[c] = *(const float4*)&col_emb[c * D + tid * 4];
    float w2r[2][C];
    #pragma unroll
    for (int r2 = 0; r2 < 2; ++r2)
        #pragma unroll
        for (int cq = 0; cq < 4; ++cq) {
            const float4 v = *(const float4*)&w2[(tid * 2 + r2) * C + cq * 4];
            w2r[r2][cq * 4 + 0] = v.x; w2r[r2][cq * 4 + 1] = v.y;
            w2r[r2][cq * 4 + 2] = v.z; w2r[r2][cq * 4 + 3] = v.w;
        }

    for (int ti = 0; ti < RT_T; ++ti) {
        const int t = t0 + ti;
        const float4 xv = *(const float4*)&x[(size_t)t * D + tid * 4];
        const unsigned hu = *(const unsigned*)&Hb[(size_t)t * DH + tid * 2];
        const float h0 = bf2f((short)(hu & 0xffff));
        const float h1 = bf2f((short)(hu >> 16));
        float pv[32];
        #pragma unroll
        for (int c = 0; c < C; ++c)
            pv[c] = xv.x * ce[c].x + xv.y * ce[c].y + xv.z * ce[c].z + xv.w * ce[c].w;
        #pragma unroll
        for (int c = 0; c < C; ++c)
            pv[C + c] = h0 * w2r[0][c] + h1 * w2r[1][c];
        float ssp = xv.x * xv.x + xv.y * xv.y + xv.z * xv.z + xv.w * xv.w;
        #pragma unroll
        for (int off = 32; off; off >>= 1) ssp += __shfl_xor(ssp, off);
        if (lane == 0) SSW[tid >> 6] = ssp;
        #pragma unroll
        for (int c = 0; c < 32; ++c)
            P[tid][c ^ swz] = pv[c];
        __syncthreads();
        {
            const int v = tid & 31, jj = tid >> 5;
            float s = 0.f;
            #pragma unroll
            for (int k = 0; k < 32; ++k) {
                const int row = jj * 32 + k;
                s += P[row][v ^ ((row & 7) << 2)];
            }
            Q[jj][v] = s;
        }
        __syncthreads();
        if (tid < 32) {
            float f = 0.f;
            #pragma unroll
            for (int j2 = 0; j2 < 8; ++j2) f += Q[j2][tid];
            FL[ti][tid] = f;
        } else if (tid == 32) {
            FL[ti][32] = SSW[0] + SSW[1] + SSW[2] + SSW[3];
        }
        __syncthreads();
    }

    if (tid < RT_T) {
        const int t = t0 + tid;
        const float xn = fmaxf(sqrtf(FL[tid][32]), 1e-12f);
        float logit[C];
        #pragma unroll
        for (int c = 0; c < C; ++c)
            logit[c] = FL[tid][c] / (xn * cnorm[c])
                     + sigmoidf_(FL[tid][C + c] + b2[c]);
        float mx = logit[0]; int am = 0;
        #pragma unroll
        for (int c = 1; c < C; ++c)
            if (logit[c] > mx) { mx = logit[c]; am = c; }
        float se = 0.f;
        #pragma unroll
        for (int c = 0; c < C; ++c) se += expf(logit[c] - mx);
        idx[t] = am;
        wgt[t] = 1.f / se;
    }
}

// ---------------------------------------------------------------------------
// histogram + prefix + packed worklist (single block)
// wl slot s belongs to bucket s%8; col c prefers bucket c&7 (XCD affinity),
// spills to next bucket when full. entry = (col<<24)|(nt<<16)|baseSlot.
// ---------------------------------------------------------------------------
__global__ __launch_bounds__(256) void hist_kernel(const int* __restrict__ idx,
        int* __restrict__ cursor, int* __restrict__ wl) {
    __shared__ int h[C];
    const int tid = threadIdx.x;
    if (tid < C) h[tid] = 0;
    for (int i = tid; i < WLG; i += 256) wl[i] = -1;
    __syncthreads();
    for (int t = tid; t < TOK; t += 256) atomicAdd(&h[idx[t]], 1);
    __syncthreads();
    if (tid == 0) {
        int s = 0;
        int slots[8] = {0, 0, 0, 0, 0, 0, 0, 0};
        for (int c = 0; c < C; ++c) {
            cursor[c] = s;
            for (int st = 0; st < h[c]; st += 64) {
                const int ntg = min(64, h[c] - st);
                int b = c & 7;
                while (slots[b] >= BCAP) b = (b + 1) & 7;
                wl[slots[b] * 8 + b] = (c << 24) | (ntg << 16) | (s + st);
                slots[b]++;
            }
            s += h[c];
        }
    }
}

// ---------------------------------------------------------------------------
// scatter: block-local ranges -> 16 global atomics per block
// ---------------------------------------------------------------------------
__global__ __launch_bounds__(256) void scatter_kernel(const int* __restrict__ idx,
        int* __restrict__ cursor, int* __restrict__ order) {
    __shared__ int lh[C];
    __shared__ int lbase[C];
    const int tid = threadIdx.x;
    const int t = blockIdx.x * 256 + tid;
    if (tid < C) lh[tid] = 0;
    __syncthreads();
    const int c = idx[t];
    const int p = atomicAdd(&lh[c], 1);
    __syncthreads();
    if (tid < C) lbase[tid] = atomicAdd(&cursor[tid], lh[tid]);
    __syncthreads();
    order[lbase[c] + p] = t;
}

// ---------------------------------------------------------------------------
// layernorm, in-place on out
// ---------------------------------------------------------------------------
__global__ __launch_bounds__(256) void ln_kernel(float* __restrict__ out,
        const float* __restrict__ g, const float* __restrict__ b) {
    __shared__ float wr_[4], wr2[4];
    const int t = blockIdx.x, tid = threadIdx.x;
    const float4 v = *(const float4*)&out[(size_t)t * D + tid * 4];
    float s = v.x + v.y + v.z + v.w;
    float s2 = v.x * v.x + v.y * v.y + v.z * v.z + v.w * v.w;
    for (int off = 32; off; off >>= 1) { s += __shfl_xor(s, off); s2 += __shfl_xor(s2, off); }
    if ((tid & 63) == 0) { wr_[tid >> 6] = s; wr2[tid >> 6] = s2; }
    __syncthreads();
    const float sum = wr_[0] + wr_[1] + wr_[2] + wr_[3];
    const float sum2 = wr2[0] + wr2[1] + wr2[2] + wr2[3];
    const float mu = sum * (1.f / D);
    const float var = sum2 * (1.f / D) - mu * mu;
    const float inv = rsqrtf(var + 1e-5f);
    const float4 g4 = *(const float4*)&g[tid * 4];
    const float4 b4 = *(const float4*)&b[tid * 4];
    float4 o;
    o.x = (v.x - mu) * inv * g4.x + b4.x;
    o.y = (v.y - mu) * inv * g4.y + b4.y;
    o.z = (v.z - mu) * inv * g4.z + b4.z;
    o.w = (v.w - mu) * inv * g4.w + b4.w;
    *(float4*)&out[(size_t)t * D + tid * 4] = o;
}

// ---------------------------------------------------------------------------
extern "C" void kernel_launch(void* const* d_in, const int* in_sizes, int n_in,
                              void* d_out, int out_size, void* d_ws, size_t ws_size,
                              hipStream_t stream) {
    const float* x       = (const float*)d_in[0];
    const float* col_emb = (const float*)d_in[1];
    const float* gate_w1 = (const float*)d_in[2];
    const float* gate_b1 = (const float*)d_in[3];
    const float* gate_w2 = (const float*)d_in[4];
    const float* gate_b2 = (const float*)d_in[5];
    const float* W_cols  = (const float*)d_in[6];
    const float* b_cols  = (const float*)d_in[7];
    const float* proj_w  = (const float*)d_in[8];
    const float* proj_b  = (const float*)d_in[9];
    const float* ln_g    = (const float*)d_in[10];
    const float* ln_b    = (const float*)d_in[11];
    float* out = (float*)d_out;

    char* w = (char*)d_ws;
    short* xb    = (short*)w;  w += (size_t)TOK * D * 2;           // 16 MB
    short* Hb    = (short*)w;  w += (size_t)TOK * DH * 2;          //  8 MB
    short* actb  = (short*)w;  w += (size_t)TOK * N * 2 + 65536;   //  4 MB + slack
    short* w1T   = (short*)w;  w += (size_t)DH * D * 2;            //  1 MB
    short* WcT   = (short*)w;  w += (size_t)C * N * D * 2;         //  8 MB
    short* pwT   = (short*)w;  w += (size_t)C * D * N * 2;         //  8 MB
    float* wgt   = (float*)w;  w += TOK * 4;
    float* cnorm = (float*)w;  w += 64;
    int*   idx   = (int*)w;    w += TOK * 4;
    int*   order = (int*)w;    w += TOK * 4;
    int*   cursor= (int*)w;    w += 64;
    int*   wl    = (int*)w;    w += WLG * 4;

    hipLaunchKernelGGL(prep_kernel, dim3(1), dim3(256), 0, stream, col_emb, cnorm);
    hipLaunchKernelGGL(conv_kernel, dim3(2048), dim3(256), 0, stream,
                       x, xb, TOK * D / 4);
    hipLaunchKernelGGL(tconv_kernel, dim3(DH / 64, D / 64, 1), dim3(256), 0, stream,
                       gate_w1, w1T, D, DH);
    hipLaunchKernelGGL(tconv_kernel, dim3(N / 64, D / 64, C), dim3(256), 0, stream,
                       W_cols, WcT, D, N);
    hipLaunchKernelGGL(tconv_kernel, dim3(D / 64, N / 64, C), dim3(256), 0, stream,
                       proj_w, pwT, N, D);
    hipLaunchKernelGGL(gate_mfma_kernel, dim3(TOK / 64, DH / 64), dim3(256), 0, stream,
                       xb, w1T, gate_b1, Hb);
    hipLaunchKernelGGL(route_kernel, dim3(TOK / RT_T), dim3(256), 0, stream,
                       x, Hb, col_emb, cnorm, gate_w2, gate_b2, idx, wgt);
    hipLaunchKernelGGL(hist_kernel, dim3(1), dim3(256), 0, stream, idx, cursor, wl);
    hipLaunchKernelGGL(scatter_kernel, dim3(TOK / 256), dim3(256), 0, stream,
                       idx, cursor, order);
    // column GEMM1 (grouped, compact worklist) -> actb
    hipLaunchKernelGGL((mfma_tile<1>), dim3(WLG, N / 64), dim3(256), 0, stream,
                       xb, WcT, b_cols, nullptr, order, wgt, wl, actb, nullptr);
    // column GEMM2 (grouped, compact worklist) -> out (+bias+residual)
    hipLaunchKernelGGL((mfma_tile<2>), dim3(WLG, D / 64), dim3(256), 0, stream,
                       actb, pwT, proj_b, x, order, wgt, wl, nullptr, out);
    hipLaunchKernelGGL(ln_kernel, dim3(TOK), dim3(256), 0, stream, out, ln_g, ln_b);
}